// Round 3
// baseline (123.615 us; speedup 1.0000x reference)
//
#include <hip/hip_runtime.h>

// LandmarkLoss fused single-kernel, round 3.
// B=4, N=200000, K=64 targets.
// Round-3 changes vs round 2:
//  * P=4 -> P=2 (128 points/wave): 1564 blocks = 6.1 waves/SIMD resident
//    (was 3.06) -- the round-2 counters showed latency-bound (VALUBusy 46%,
//    occupancy 21%), so buy TLP with a finer grid.
//  * pd2 tracked WITHOUT the per-point |p|^2 term (min is shift-invariant;
//    added back in epilogue): 3 FMA/pair instead of 4.
//  * g2p accumulated via atomicMax over ~bits(g) (monotone-decreasing encode
//    for non-negative floats) so d_ws init is ONE zero-memset.
//  * __launch_bounds__(256,6), unroll 8 for LDS batching.

constexpr int KT = 64;
constexpr int P  = 2;
constexpr float DIST_THRESH = 0.1f;
constexpr float W_DIST    = 0.05f;
constexpr float W_CHAMFER = 0.05f;
constexpr float W_SEP     = 0.0005f;
constexpr float PT_SENT = 1e18f;   // dummy-point sentinel (tail lanes)
constexpr float TG_SENT = -1e18f;  // invalid-target sentinel
constexpr float BIGF = 3.0e38f;

__global__ __launch_bounds__(256, 6)
void landmark_fused(const float* __restrict__ C, const float* __restrict__ F,
                    const float* __restrict__ tC, const int* __restrict__ tF,
                    const int* __restrict__ classes, int n_classes,
                    int B, int N, int bpb, int cpb,
                    unsigned int* __restrict__ g2p_ws, float* __restrict__ sums,
                    unsigned int* __restrict__ ticket, float* __restrict__ out)
{
    __shared__ float4 tgt[KT];
    __shared__ float gredw[4][KT];
    __shared__ float rs[3][4];
    __shared__ int is_last;
    __shared__ float lossb[4];

    const int tid  = threadIdx.x;
    const int lane = tid & 63;
    const int wib  = tid >> 6;
    const int b    = blockIdx.x / bpb;
    const int waves_per_batch = bpb * 4;
    const int wid  = (blockIdx.x - b * bpb) * 4 + wib;

    // Stage this batch's 64 targets: (-2tx,-2ty,-2tz, |t|^2), sentinel if invalid.
    if (tid < KT) {
        int f = tF[b * KT + tid];
        bool valid = false;
        for (int c = 0; c < n_classes; ++c) valid = valid || (f == classes[c]);
        float x = TG_SENT, y = TG_SENT, z = TG_SENT;
        if (valid) {
            x = tC[(b * KT + tid) * 3 + 0];
            y = tC[(b * KT + tid) * 3 + 1];
            z = tC[(b * KT + tid) * 3 + 2];
        }
        tgt[tid] = make_float4(-2.f * x, -2.f * y, -2.f * z,
                               x * x + y * y + z * z);
    }
    __syncthreads();

    const float*  Cb = C + (size_t)b * N * 3;
    const float4* Fb = (const float4*)(F + (size_t)b * N * 4);

    float gmin = BIGF;                       // g2p min (true ld2) for target k == lane
    float dist_acc = 0.f, p2g_acc = 0.f, sep_acc = 0.f;

    for (int chunk = wid; chunk < cpb; chunk += waves_per_batch) {
        const int base = chunk * (64 * P);

        float px[P], py[P], pz[P], pp[P], cx[P], cy[P], cz[P], cc[P], f0[P];
        bool  vp[P];
        #pragma unroll
        for (int p = 0; p < P; ++p) {
            int n = base + p * 64 + lane;
            bool v = (n < N);
            vp[p] = v;
            int ni = v ? n : 0;
            float4 f4 = Fb[ni];
            float X = Cb[3 * ni + 0], Y = Cb[3 * ni + 1], Z = Cb[3 * ni + 2];
            f0[p] = f4.x;
            if (!v) { X = PT_SENT; Y = PT_SENT; Z = PT_SENT; f4.y = f4.z = f4.w = 0.f; }
            px[p] = X;          py[p] = Y;          pz[p] = Z;
            cx[p] = X + f4.y;   cy[p] = Y + f4.z;   cz[p] = Z + f4.w;
            pp[p] = fmaf(pz[p], pz[p], fmaf(py[p], py[p], px[p] * px[p]));
            cc[p] = fmaf(cz[p], cz[p], fmaf(cy[p], cy[p], cx[p] * cx[p]));
        }

        // m1/m2 track pd2' = tt - 2 p.t   (offset by constant pp[p]: ordering equal)
        // l1/l2/lmin track ld2' = tt - 2 c.t (offset by constant cc[p])
        float m1[P], m2[P], l1[P], l2[P], lmin[P];
        #pragma unroll
        for (int p = 0; p < P; ++p) {
            m1[p] = BIGF; m2[p] = BIGF; l1[p] = BIGF; l2[p] = BIGF; lmin[p] = BIGF;
        }

        int kk = lane;
        #pragma unroll 8
        for (int i = 0; i < 64; ++i) {
            float4 T = tgt[kk];
            float dl = BIGF;        // min over p of TRUE ld2, for target kk
            #pragma unroll
            for (int p = 0; p < P; ++p) {
                float pd2 = fmaf(px[p], T.x, fmaf(py[p], T.y, fmaf(pz[p], T.z, T.w)));
                float ld2 = fmaf(cx[p], T.x, fmaf(cy[p], T.y, fmaf(cz[p], T.z, T.w)));
                bool c1 = pd2 < m1[p];
                bool c2 = pd2 < m2[p];
                float hi = fmaxf(m1[p], pd2);
                m1[p] = fminf(m1[p], pd2);
                m2[p] = fminf(m2[p], hi);
                float tsel = c1 ? l1[p] : ld2;
                l2[p] = c2 ? tsel : l2[p];
                l1[p] = c1 ? ld2 : l1[p];
                lmin[p] = fminf(lmin[p], ld2);
                dl = fminf(dl, ld2 + cc[p]);   // re-add constant for cross-p compare
            }
            float got = __shfl(dl, (lane - i) & 63, 64);
            gmin = fminf(gmin, got);
            kk = (kk + 1) & 63;
        }

        #pragma unroll
        for (int p = 0; p < P; ++p) {
            float mind = sqrtf(fmaxf(m1[p] + pp[p], 0.f));
            bool pm = mind < DIST_THRESH;
            float tgtv = fminf(mind, 2.0f * DIST_THRESH);
            float diff = f0[p] - tgtv;
            float ad = fabsf(diff);
            float sl1 = (ad < 1.0f) ? 0.5f * diff * diff : (ad - 0.5f);
            if (vp[p]) dist_acc += sl1;
            if (pm) {                               // pm false for dummy points
                p2g_acc += fmaxf(lmin[p] + cc[p], 0.f);
                sep_acc += sqrtf(fmaxf(l1[p] + cc[p], 0.f)) /
                           sqrtf(fmaxf(l2[p] + cc[p], 1e-30f));
            }
        }
    }

    // ---- block-level reduction ----
    float v0 = dist_acc, v1 = p2g_acc, v2 = sep_acc;
    #pragma unroll
    for (int o = 32; o > 0; o >>= 1) {
        v0 += __shfl_down(v0, o, 64);
        v1 += __shfl_down(v1, o, 64);
        v2 += __shfl_down(v2, o, 64);
    }
    if (lane == 0) { rs[0][wib] = v0; rs[1][wib] = v1; rs[2][wib] = v2; }
    gredw[wib][lane] = gmin;
    __syncthreads();

    if (tid < 3) {
        float s = rs[tid][0] + rs[tid][1] + rs[tid][2] + rs[tid][3];
        atomicAdd(&sums[tid * B + b], s);
    }
    if (tid < KT) {
        float g = fminf(fminf(gredw[0][tid], gredw[1][tid]),
                        fminf(gredw[2][tid], gredw[3][tid]));
        g = fmaxf(g, 0.f);
        // encode: ~bits(g) is monotone DECREASING for g>=0, so atomicMax
        // accumulates the minimum; init value 0 loses to every encode.
        atomicMax(&g2p_ws[b * KT + tid], ~__float_as_uint(g));
    }

    // ---- ticket: last block finalizes ----
    if (tid == 0) {
        __threadfence();
        unsigned int t = atomicAdd(ticket, 1u);
        is_last = (t == (unsigned int)(gridDim.x - 1));
    }
    __syncthreads();
    if (!is_last) return;

    {
        const int fb = tid >> 6, fk = tid & 63;
        float g = 0.f, nv = 0.f;
        if (fb < B) {
            int f = tF[fb * KT + fk];
            bool valid = false;
            for (int c = 0; c < n_classes; ++c) valid = valid || (f == classes[c]);
            if (valid) {
                nv = 1.f;
                // atomic no-op read (device-coherent): max with 0 returns old
                unsigned int enc = atomicMax(&g2p_ws[fb * KT + fk], 0u);
                g = __uint_as_float(~enc);
            }
        }
        #pragma unroll
        for (int o = 32; o > 0; o >>= 1) {
            g  += __shfl_down(g, o, 64);
            nv += __shfl_down(nv, o, 64);
        }
        if (fb < B && fk == 0) {
            float sd = atomicAdd(&sums[0 * B + fb], 0.f);
            float sp = atomicAdd(&sums[1 * B + fb], 0.f);
            float ss = atomicAdd(&sums[2 * B + fb], 0.f);
            float sep = (nv >= 2.f) ? ss : 0.f;
            lossb[fb] = W_DIST * sd + W_CHAMFER * (sp + g) + W_SEP * sep;
        }
        __syncthreads();
        if (tid == 0) {
            float s = 0.f;
            for (int i = 0; i < B; ++i) s += lossb[i];
            out[0] = s / (float)B;
        }
    }
}

extern "C" void kernel_launch(void* const* d_in, const int* in_sizes, int n_in,
                              void* d_out, int out_size, void* d_ws, size_t ws_size,
                              hipStream_t stream)
{
    const float* C       = (const float*)d_in[0];   // (B,N,3)
    const float* F       = (const float*)d_in[1];   // (B,N,4)
    const float* tC      = (const float*)d_in[2];   // (B,K,3)
    const int*   tF      = (const int*)d_in[3];     // (B,K)
    const int*   classes = (const int*)d_in[4];     // (6,)
    const int n_classes = in_sizes[4];
    const int B = 4;
    const int N = in_sizes[0] / (3 * B);            // 200000

    unsigned int* g2p_ws = (unsigned int*)d_ws;                 // 256 u32
    float*        sums   = (float*)((char*)d_ws + KT * B * 4);  // 12 f32
    unsigned int* ticket = (unsigned int*)((char*)d_ws + KT * B * 4 + 12 * 4);

    // One memset: g2p encode-max init 0, sums 0, ticket 0.
    hipMemsetAsync(d_ws, 0, KT * B * 4 + 16 * 4, stream);

    const int cpb = (N + 64 * P - 1) / (64 * P);    // 1563 chunks per batch
    const int bpb = (cpb + 3) / 4;                  // 391 blocks/batch, 1 chunk/wave
    landmark_fused<<<bpb * B, 256, 0, stream>>>(C, F, tC, tF, classes, n_classes,
                                                B, N, bpb, cpb, g2p_ws, sums, ticket,
                                                (float*)d_out);
}

// Round 4
// 107.062 us; speedup vs baseline: 1.1546x; 1.1546x over previous
//
#include <hip/hip_runtime.h>

// LandmarkLoss fused single-kernel, round 4.
// B=4, N=200000, K=64 targets.
// Round-4 changes vs round 2/3:
//  * Back to P=4 (round 3 showed P=2 doubles per-iteration overhead and
//    per-CU LDS-pipe traffic: VALU busy-time ROSE 20.4->23.5 us).
//  * Key-packing: key = (bits(pd2f) & ~63) | k. min/2nd-min via 3 uint
//    min/max ops -- replaces the 2 v_cmp + 3 v_cndmask companion chain.
//    Companion ld2 values recomputed in the epilogue from k1&63 / k2&63.
//    pd2f kept positive by storing |t|^2 + 16 as T.w (valid pd2f >= ~9.8).
//    6-bit mantissa truncation error ~6e-5 absolute -- tolerance is 3.34.
//  * tgt2[128] doubled array: rotated LDS read address is linear
//    (lane*16 + i*16), pure immediate offsets under unroll, no mod math.
//  * Dummy-point sentinel = -1e18 (dot-form distances stay positive-huge);
//    pm guarded with vp.

constexpr int KT = 64;
constexpr int P  = 4;
constexpr float DIST_THRESH = 0.1f;
constexpr float W_DIST    = 0.05f;
constexpr float W_CHAMFER = 0.05f;
constexpr float W_SEP     = 0.0005f;
constexpr float PT_SENT = -1e18f;  // dummy-point sentinel (tail lanes)
constexpr float TG_SENT = -1e18f;  // invalid-target sentinel
constexpr float BIGF  = 3.0e38f;
constexpr float WBIAS = 16.0f;     // |t|^2 + WBIAS stored in T.w keeps keyf > 0

__device__ __forceinline__ unsigned umin_(unsigned a, unsigned b) { return a < b ? a : b; }
__device__ __forceinline__ unsigned umax_(unsigned a, unsigned b) { return a > b ? a : b; }

__global__ __launch_bounds__(256, 4)
void landmark_fused(const float* __restrict__ C, const float* __restrict__ F,
                    const float* __restrict__ tC, const int* __restrict__ tF,
                    const int* __restrict__ classes, int n_classes,
                    int B, int N, int bpb, int cpb,
                    unsigned int* __restrict__ g2p_ws, float* __restrict__ sums,
                    unsigned int* __restrict__ ticket, float* __restrict__ out)
{
    __shared__ float4 tgt2[2 * KT];      // doubled: tgt2[j] == tgt2[j+64]
    __shared__ float gredw[4][KT];
    __shared__ float rs[3][4];
    __shared__ int is_last;
    __shared__ float lossb[4];

    const int tid  = threadIdx.x;
    const int lane = tid & 63;
    const int wib  = tid >> 6;
    const int b    = blockIdx.x / bpb;
    const int waves_per_batch = bpb * 4;
    const int wid  = (blockIdx.x - b * bpb) * 4 + wib;

    // Stage 64 targets: (-2tx,-2ty,-2tz, |t|^2 + WBIAS), sentinel if invalid.
    if (tid < KT) {
        int f = tF[b * KT + tid];
        bool valid = false;
        for (int c = 0; c < n_classes; ++c) valid = valid || (f == classes[c]);
        float x = TG_SENT, y = TG_SENT, z = TG_SENT;
        if (valid) {
            x = tC[(b * KT + tid) * 3 + 0];
            y = tC[(b * KT + tid) * 3 + 1];
            z = tC[(b * KT + tid) * 3 + 2];
        }
        float4 v = make_float4(-2.f * x, -2.f * y, -2.f * z,
                               x * x + y * y + z * z + WBIAS);
        tgt2[tid] = v;
        tgt2[tid + KT] = v;
    }
    __syncthreads();

    const float*  Cb = C + (size_t)b * N * 3;
    const float4* Fb = (const float4*)(F + (size_t)b * N * 4);

    float gmin = BIGF;                       // g2p min (true ld2) for target k == lane
    float dist_acc = 0.f, p2g_acc = 0.f, sep_acc = 0.f;

    for (int chunk = wid; chunk < cpb; chunk += waves_per_batch) {
        const int base = chunk * (64 * P);

        float px[P], py[P], pz[P], ppm[P], cx[P], cy[P], cz[P], ccm[P], f0[P];
        bool  vp[P];
        #pragma unroll
        for (int p = 0; p < P; ++p) {
            int n = base + p * 64 + lane;
            bool v = (n < N);
            vp[p] = v;
            int ni = v ? n : 0;
            float4 f4 = Fb[ni];
            float X = Cb[3 * ni + 0], Y = Cb[3 * ni + 1], Z = Cb[3 * ni + 2];
            f0[p] = f4.x;
            if (!v) { X = PT_SENT; Y = PT_SENT; Z = PT_SENT; f4.y = f4.z = f4.w = 0.f; }
            px[p] = X;          py[p] = Y;          pz[p] = Z;
            cx[p] = X + f4.y;   cy[p] = Y + f4.z;   cz[p] = Z + f4.w;
            ppm[p] = fmaf(pz[p], pz[p], fmaf(py[p], py[p], px[p] * px[p])) - WBIAS;
            ccm[p] = fmaf(cz[p], cz[p], fmaf(cy[p], cy[p], cx[p] * cx[p])) - WBIAS;
        }

        // keyf = |t|^2 + WBIAS - 2 p.t  (== true pd2 - |p|^2 + WBIAS > 0 for real data)
        // ld2' = |t|^2 + WBIAS - 2 c.t  (true ld2 = ld2' + ccm)
        unsigned k1[P], k2[P];
        float lmin[P];
        #pragma unroll
        for (int p = 0; p < P; ++p) { k1[p] = 0xFFFFFFFFu; k2[p] = 0xFFFFFFFFu; lmin[p] = BIGF; }

        #pragma unroll 8
        for (int i = 0; i < 64; ++i) {
            const float4 T = tgt2[lane + i];         // linear addr, imm offsets
            const unsigned kk = (unsigned)((lane + i) & 63);
            float dl = BIGF;                          // min over p of TRUE ld2 for target kk
            #pragma unroll
            for (int p = 0; p < P; ++p) {
                float keyf = fmaf(px[p], T.x, fmaf(py[p], T.y, fmaf(pz[p], T.z, T.w)));
                float ld2  = fmaf(cx[p], T.x, fmaf(cy[p], T.y, fmaf(cz[p], T.z, T.w)));
                unsigned key = (__float_as_uint(keyf) & 0xFFFFFFC0u) | kk;
                unsigned hi = umax_(k1[p], key);
                k1[p] = umin_(k1[p], key);
                k2[p] = umin_(k2[p], hi);
                lmin[p] = fminf(lmin[p], ld2);
                dl = fminf(dl, ld2 + ccm[p]);
            }
            float got = __shfl(dl, (lane - i) & 63, 64);
            gmin = fminf(gmin, got);
        }

        #pragma unroll
        for (int p = 0; p < P; ++p) {
            float keyf1 = __uint_as_float(k1[p] & 0xFFFFFFC0u);
            float mind = sqrtf(fmaxf(keyf1 + ppm[p], 0.f));
            bool pm = (mind < DIST_THRESH) && vp[p];
            float tgtv = fminf(mind, 2.0f * DIST_THRESH);
            float diff = f0[p] - tgtv;
            float ad = fabsf(diff);
            float sl1 = (ad < 1.0f) ? 0.5f * diff * diff : (ad - 0.5f);
            if (vp[p]) dist_acc += sl1;
            if (pm) {
                p2g_acc += fmaxf(lmin[p] + ccm[p], 0.f);
                int i1 = (int)(k1[p] & 63u), i2 = (int)(k2[p] & 63u);
                float4 T1 = tgt2[i1], T2 = tgt2[i2];
                float l1sq = fmaf(cx[p], T1.x, fmaf(cy[p], T1.y, fmaf(cz[p], T1.z, T1.w))) + ccm[p];
                float l2sq = fmaf(cx[p], T2.x, fmaf(cy[p], T2.y, fmaf(cz[p], T2.z, T2.w))) + ccm[p];
                sep_acc += sqrtf(fmaxf(l1sq, 0.f) / fmaxf(l2sq, 1e-30f));
            }
        }
    }

    // ---- block-level reduction ----
    float v0 = dist_acc, v1 = p2g_acc, v2 = sep_acc;
    #pragma unroll
    for (int o = 32; o > 0; o >>= 1) {
        v0 += __shfl_down(v0, o, 64);
        v1 += __shfl_down(v1, o, 64);
        v2 += __shfl_down(v2, o, 64);
    }
    if (lane == 0) { rs[0][wib] = v0; rs[1][wib] = v1; rs[2][wib] = v2; }
    gredw[wib][lane] = gmin;
    __syncthreads();

    if (tid < 3) {
        float s = rs[tid][0] + rs[tid][1] + rs[tid][2] + rs[tid][3];
        atomicAdd(&sums[tid * B + b], s);
    }
    if (tid < KT) {
        float g = fminf(fminf(gredw[0][tid], gredw[1][tid]),
                        fminf(gredw[2][tid], gredw[3][tid]));
        g = fmaxf(g, 0.f);
        // ~bits(g) is monotone decreasing for g>=0: atomicMax accumulates min;
        // init 0 loses to every encode.
        atomicMax(&g2p_ws[b * KT + tid], ~__float_as_uint(g));
    }

    // ---- ticket: last block finalizes ----
    if (tid == 0) {
        __threadfence();
        unsigned int t = atomicAdd(ticket, 1u);
        is_last = (t == (unsigned int)(gridDim.x - 1));
    }
    __syncthreads();
    if (!is_last) return;

    {
        const int fb = tid >> 6, fk = tid & 63;
        float g = 0.f, nv = 0.f;
        if (fb < B) {
            int f = tF[fb * KT + fk];
            bool valid = false;
            for (int c = 0; c < n_classes; ++c) valid = valid || (f == classes[c]);
            if (valid) {
                nv = 1.f;
                unsigned int enc = atomicMax(&g2p_ws[fb * KT + fk], 0u);  // atomic read
                g = __uint_as_float(~enc);
            }
        }
        #pragma unroll
        for (int o = 32; o > 0; o >>= 1) {
            g  += __shfl_down(g, o, 64);
            nv += __shfl_down(nv, o, 64);
        }
        if (fb < B && fk == 0) {
            float sd = atomicAdd(&sums[0 * B + fb], 0.f);
            float sp = atomicAdd(&sums[1 * B + fb], 0.f);
            float ss = atomicAdd(&sums[2 * B + fb], 0.f);
            float sep = (nv >= 2.f) ? ss : 0.f;
            lossb[fb] = W_DIST * sd + W_CHAMFER * (sp + g) + W_SEP * sep;
        }
        __syncthreads();
        if (tid == 0) {
            float s = 0.f;
            for (int i = 0; i < B; ++i) s += lossb[i];
            out[0] = s / (float)B;
        }
    }
}

extern "C" void kernel_launch(void* const* d_in, const int* in_sizes, int n_in,
                              void* d_out, int out_size, void* d_ws, size_t ws_size,
                              hipStream_t stream)
{
    const float* C       = (const float*)d_in[0];   // (B,N,3)
    const float* F       = (const float*)d_in[1];   // (B,N,4)
    const float* tC      = (const float*)d_in[2];   // (B,K,3)
    const int*   tF      = (const int*)d_in[3];     // (B,K)
    const int*   classes = (const int*)d_in[4];     // (6,)
    const int n_classes = in_sizes[4];
    const int B = 4;
    const int N = in_sizes[0] / (3 * B);            // 200000

    unsigned int* g2p_ws = (unsigned int*)d_ws;                 // 256 u32
    float*        sums   = (float*)((char*)d_ws + KT * B * 4);  // 12 f32
    unsigned int* ticket = (unsigned int*)((char*)d_ws + KT * B * 4 + 12 * 4);

    hipMemsetAsync(d_ws, 0, KT * B * 4 + 16 * 4, stream);

    const int cpb = (N + 64 * P - 1) / (64 * P);    // 782 chunks per batch
    const int bpb = (cpb + 3) / 4;                  // 196 blocks/batch, 1 chunk/wave
    landmark_fused<<<bpb * B, 256, 0, stream>>>(C, F, tC, tF, classes, n_classes,
                                                B, N, bpb, cpb, g2p_ws, sums, ticket,
                                                (float*)d_out);
}